// Round 7
// baseline (104.181 us; speedup 1.0000x reference)
//
#include <hip/hip_runtime.h>
#include <math.h>

#define N 8
#define C 128
#define L 1024
#define K 100
#define TEMP 0.5f
#define EPS 1e-8f
#define NT (N * L)
#define ROWS 32   // c-rows per gemm_gather block; fp16 dot tile = 32*1024*2 = 64 KB

typedef _Float16 half8 __attribute__((ext_vector_type(8)));
typedef float f32x4 __attribute__((ext_vector_type(4)));

// ============================================================================
// MEASUREMENT ROUND: kernels are byte-identical to round 6 (73.8 us). The
// launcher replicates transpose x3 and gemm x4 (both idempotent) to solve the
// per-node marginal costs:  dur - 73.8 = 2*T_t + 3*T_g.  This resolves whether
// the residual-after-fill (~31 us) is kernel time (attack gemm next) or
// harness reset/gap floor (declare roofline next).
// ============================================================================

// Fragment layout (half8 units): idx = ((n*64 + tile)*4 + ks)*64 + (r16 + 16*kg)
// holds element (l = tile*16 + r16, ch = ks*32 + kg*8 + e) in slot e.
// This IS the mfma_f32_16x16x32_f16 A/B operand order: lane r16+16*kg reads
// its own half8 with a fully-coalesced 1-KB wave load.

// Transpose + fp16 convert into fragment layout + fp32 row-norm partials.
// 1-D grid, 512 blocks: d&7 = n, (d>>3)&1 = which (0:z, 1:c), rest = tile coords.
__global__ void __launch_bounds__(512)
transpose_frag(const float* __restrict__ z, const float* __restrict__ c,
               half8* __restrict__ zf, half8* __restrict__ cf,
               float* __restrict__ zp, float* __restrict__ cp) {
    __shared__ float tile[64][65];
    __shared__ float part[8][64];
    const int d = blockIdx.x;
    const int n = d & 7;
    const int rest = d >> 3;              // 0..63
    const int which = rest & 1;
    const int c0 = ((rest >> 1) & 1) * 64;
    const int l0 = (rest >> 2) * 64;      // 0..15 -> *64
    const float* src = which ? c : z;
    half8* dst = which ? cf : zf;
    float* pdst = which ? cp : zp;
    const int slen = which ? (L + 1) : L;
    const int off = which;
    const int tx = threadIdx.x;   // 0..63  (local l)
    const int ty = threadIdx.y;   // 0..7   (8-channel chunk)
#pragma unroll
    for (int i = 0; i < 8; i++) {
        int chn = c0 + ty + i * 8;
        tile[ty + i * 8][tx] = src[((size_t)(n * C + chn)) * slen + off + l0 + tx];
    }
    __syncthreads();
    // thread (tx,ty): l = l0+tx, channels c0+ty*8 .. +7 -> one half8 fragment store
    float p = 0.f;
    half8 hv;
#pragma unroll
    for (int q = 0; q < 8; q++) {
        float v = tile[ty * 8 + q][tx];   // 2 lanes/bank: free (m136)
        p += v * v;
        hv[q] = (_Float16)v;
    }
    const int l = l0 + tx;
    const int ch = c0 + ty * 8;
    const int ks = ch >> 5, kg = (ch >> 3) & 3;
    dst[(((size_t)(n * 64 + (l >> 4)) * 4 + ks) << 6) + (l & 15) + (kg << 4)] = hv;
    part[ty][tx] = p;   // partial ||.||^2 over this thread's 8 channels
    __syncthreads();
    if (ty == 0) {
        float sm = 0.f;
#pragma unroll
        for (int i = 0; i < 8; i++) sm += part[i][tx];
        pdst[(((size_t)n << 10) + l0 + tx) * 2 + (c0 >> 6)] = sm;
    }
}

// Dense MFMA GEMM: 32 c-rows x 1024 z-rows, K=128, then fully-LDS gather of
// 101 cols/row. All global traffic flat-coalesced; slab reads L2-local via
// XCD pinning (n = blockIdx.x & 7).
__global__ void __launch_bounds__(512, 2)
gemm_gather(const half8* __restrict__ zf, const half8* __restrict__ cf,
            const int* __restrict__ neg_inds,
            const float* __restrict__ zp, const float* __restrict__ cp,
            const float* __restrict__ z_orig, const float* __restrict__ c_orig,
            float* __restrict__ out) {
    __shared__ _Float16 dotH[ROWS * L];     // 64 KB fp16 dot tile (kg-swizzled)
    __shared__ float ztn[L];                // 4 KB  ||z_col||^2
    __shared__ float ztr[L];                // 4 KB  rsqrt(max(tn, eps^2))
    __shared__ int   nil[ROWS * K];         // 12.8 KB staged neg_inds slab
    __shared__ float outF[ROWS * (K + 1)];  // 12.9 KB staged output slab
    const int tid  = threadIdx.x;
    const int lane = tid & 63;
    const int w    = tid >> 6;            // wave 0..7, owns cols [w*128, w*128+128)
    const int n    = blockIdx.x & 7;      // XCD-pinned: all blocks of slab n -> XCD n
    const int tA   = blockIdx.x >> 3;     // c-row tile: rows [tA*32, tA*32+32)
    const int ntg0 = (n << 10) + (tA << 5);

    // --- coalesced staging (issued early; latency hides under the MFMA loop) ---
    const float2* zp2 = (const float2*)zp + ((size_t)n << 10);
    for (int i = tid; i < L; i += 512) {
        float2 tv = zp2[i];
        float tn = tv.x + tv.y;
        ztn[i] = tn;
        ztr[i] = rsqrtf(fmaxf(tn, EPS * EPS));
    }
    const int* nb = neg_inds + (size_t)ntg0 * K;
    for (int i = tid; i < ROWS * K; i += 512) nil[i] = nb[i];

    // --- GEMM ---
    const size_t nbase = (size_t)n << 14;          // n * 64 tiles * 4 ks * 64 lanes
    half8 a[2][4];
#pragma unroll
    for (int at = 0; at < 2; at++)
#pragma unroll
        for (int ks = 0; ks < 4; ks++)             // 8 coalesced 1-KB loads
            a[at][ks] = cf[nbase + ((((tA << 1) + at) * 4 + ks) << 6) + lane];

    f32x4 acc[2][8];
#pragma unroll
    for (int at = 0; at < 2; at++)
#pragma unroll
        for (int i = 0; i < 8; i++)
#pragma unroll
            for (int r = 0; r < 4; r++) acc[at][i][r] = 0.f;

#pragma unroll
    for (int ks = 0; ks < 4; ks++) {
        half8 b[8];
#pragma unroll
        for (int nt = 0; nt < 8; nt++)             // 8 coalesced 1-KB loads
            b[nt] = zf[nbase + ((size_t)(((w << 3) + nt) * 4 + ks) << 6) + lane];
#pragma unroll
        for (int nt = 0; nt < 8; nt++)
            acc[0][nt] = __builtin_amdgcn_mfma_f32_16x16x32_f16(a[0][ks], b[nt], acc[0][nt], 0, 0, 0);
#pragma unroll
        for (int nt = 0; nt < 8; nt++)
            acc[1][nt] = __builtin_amdgcn_mfma_f32_16x16x32_f16(a[1][ks], b[nt], acc[1][nt], 0, 0, 0);
    }

    // Park dot tile: lane (r16,kg), reg r of acc[at][nt] ->
    // D[at*16+4*kg+r][w*128+nt*16+r16], column XOR-swizzled by kg so the 64
    // lanes of each b16 store hit 32 distinct banks (2 lanes/dword: free).
    const int r16 = lane & 15;
    const int kg  = lane >> 4;
#pragma unroll
    for (int at = 0; at < 2; at++)
#pragma unroll
        for (int nt = 0; nt < 8; nt++)
#pragma unroll
            for (int r = 0; r < 4; r++) {
                const int row = (at << 4) + (kg << 2) + r;
                const int col = (w << 7) + (nt << 4) + r16;
                dotH[row * L + (col ^ (kg << 4))] = (_Float16)acc[at][nt][r];
            }
    __syncthreads();

    // --- gather phase: 16 threads per c-row, contiguous kk ranges ---
    const int row = tid >> 4;             // 0..31
    const int sub = tid & 15;             // 0..15
    const int t   = (tA << 5) + row;
    const int ksw = ((row >> 2) & 3) << 4;   // kg-swizzle for this row
    const float2 cpv = ((const float2*)cp)[ntg0 + row];
    const float cn = cpv.x + cpv.y;                           // fp32 ||c||^2
    const float rs_c = 2.0f * rsqrtf(fmaxf(cn, EPS * EPS));   // 1/(TEMP*sqrt(cn))

#pragma unroll
    for (int j = 0; j < 7; j++) {
        const int kk = sub * 7 + j;       // stride-7 across lanes: conflict-light
        if (kk <= K) {
            const int col = (kk == 0) ? t : nil[row * K + kk - 1];
            const float dot = (float)dotH[row * L + (col ^ ksw)];
            const float tn = ztn[col];
            float logit = dot * rs_c * ztr[col];
            if (kk > 0) {
                const float ds = cn - 2.f * dot + tn;         // ~0 iff c == z_col
                if (ds < 0.05f * cn) {                        // rare: exact recheck
                    bool eq = true;
                    for (int q = 0; q < C; q++) {
                        float cv = c_orig[((size_t)(n * C + q)) * (L + 1) + t + 1];
                        float zv = z_orig[((size_t)(n * C + q)) * L + col];
                        eq = eq && (cv == zv);
                    }
                    if (eq) logit = -INFINITY;
                }
            }
            outF[row * (K + 1) + kk] = logit;
        }
    }
    __syncthreads();

    // --- flat coalesced writeback of the contiguous 32x101 output slab ---
    float* ob = out + (size_t)ntg0 * (K + 1);
    for (int i = tid; i < ROWS * (K + 1); i += 512) ob[i] = outF[i];
}

extern "C" void kernel_launch(void* const* d_in, const int* in_sizes, int n_in,
                              void* d_out, int out_size, void* d_ws, size_t ws_size,
                              hipStream_t stream) {
    const float* z   = (const float*)d_in[0];   // (N, C, L)
    const float* c   = (const float*)d_in[1];   // (N, C, L+1)
    const int*   neg = (const int*)d_in[2];     // (N, L, K)
    float* out = (float*)d_out;                 // (N*L, K+1)

    half8* zf = (half8*)d_ws;                   // fragment-layout z, 2 MB
    half8* cf = zf + (size_t)N * 16384;         // fragment-layout c, 2 MB
    float* zp = (float*)(cf + (size_t)N * 16384);  // (N*L, 2) fp32 norm partials
    float* cp = zp + (size_t)NT * 2;            // (N*L, 2) fp32 norm partials

    // --- replication probe: transpose x3, gemm x4 (both idempotent) ---
    // dur - dur_R6 = 2*T_transpose + 3*T_gemm  (marginal node costs incl. gaps)
    for (int rep = 0; rep < 3; rep++)
        transpose_frag<<<dim3(512), dim3(64, 8), 0, stream>>>(z, c, zf, cf, zp, cp);
    for (int rep = 0; rep < 4; rep++)
        gemm_gather<<<dim3(N * (L / ROWS)), 512, 0, stream>>>(zf, cf, neg, zp, cp, z, c, out);
}

// Round 8
// 74.372 us; speedup vs baseline: 1.4008x; 1.4008x over previous
//
#include <hip/hip_runtime.h>
#include <math.h>

#define N 8
#define C 128
#define L 1024
#define K 100
#define TEMP 0.5f
#define EPS 1e-8f
#define NT (N * L)
#define ROWS 32   // c-rows per gemm block; fp16 dot tile = 32*1024*2 = 64 KB

typedef _Float16 half8 __attribute__((ext_vector_type(8)));
typedef float f32x4 __attribute__((ext_vector_type(4)));

// Round-7 probe resolved the decomposition: harness floor ~62.5 us (poison
// fill 43 + restore/gaps ~19), T_transpose ~3.5, T_gemm ~7.8. This round
// removes the c-side intermediate entirely: gemm blocks transpose their OWN
// 32 c-rows in-block (block-local, no sync hazards), transpose kernel is
// z-only (half the blocks/traffic), cf/cp workspace eliminated.

// Fragment layout for z (half8 units): idx = ((n*64+tile)*4+ks)*64 + (r16+16*kg)
// holds element (l = tile*16 + r16, ch = ks*32 + kg*8 + e) in slot e — the
// mfma_f32_16x16x32_f16 operand order; lane r16+16kg reads its half8 with a
// fully-coalesced 1-KB wave load. XCD pinning: n = blockIdx.x & 7 keeps all
// blocks of slab n on XCD n (slab stays in that XCD's 4-MB L2).

__global__ void __launch_bounds__(512)
transpose_z(const float* __restrict__ z, half8* __restrict__ zf,
            float* __restrict__ zp) {
    __shared__ float tile[64][65];
    __shared__ float part[8][64];
    const int d = blockIdx.x;          // 256 blocks
    const int n = d & 7;               // XCD-pinned
    const int rest = d >> 3;           // 0..31
    const int c0 = (rest & 1) * 64;
    const int l0 = (rest >> 1) * 64;   // 0..15 -> *64
    const int tx = threadIdx.x;        // 0..63 (local l)
    const int ty = threadIdx.y;        // 0..7  (8-channel chunk)
#pragma unroll
    for (int i = 0; i < 8; i++) {
        int chn = c0 + ty + i * 8;
        tile[ty + i * 8][tx] = z[((size_t)(n * C + chn)) * L + l0 + tx];
    }
    __syncthreads();
    float p = 0.f;
    half8 hv;
#pragma unroll
    for (int q = 0; q < 8; q++) {
        float v = tile[ty * 8 + q][tx];   // 2 lanes/bank: free (m136)
        p += v * v;
        hv[q] = (_Float16)v;
    }
    const int l = l0 + tx;
    const int ch = c0 + ty * 8;
    const int ks = ch >> 5, kg = (ch >> 3) & 3;
    zf[(((size_t)(n * 64 + (l >> 4)) * 4 + ks) << 6) + (l & 15) + (kg << 4)] = hv;
    part[ty][tx] = p;
    __syncthreads();
    if (ty == 0) {
        float sm = 0.f;
#pragma unroll
        for (int i = 0; i < 8; i++) sm += part[i][tx];
        zp[(((size_t)n << 10) + l0 + tx) * 2 + (c0 >> 6)] = sm;
    }
}

// 32 c-rows x 1024 z-rows GEMM + fully-LDS gather. c-rows transposed in-block
// from c_orig (ct aliased into dotH's dead space); B operand from zf (L2-local).
__global__ void __launch_bounds__(512, 1)
gemm_gather(const half8* __restrict__ zf, const int* __restrict__ neg_inds,
            const float* __restrict__ zp,
            const float* __restrict__ z_orig, const float* __restrict__ c_orig,
            float* __restrict__ out) {
    __shared__ _Float16 dotH[ROWS * L];     // 64 KB fp16 dot tile (kg-swizzled)
    __shared__ float ztn[L];                // 4 KB  ||z_col||^2
    __shared__ float ztr[L];                // 4 KB  rsqrt(max(tn, eps^2))
    __shared__ int   nil[ROWS * K];         // 12.8 KB staged neg_inds slab
    __shared__ float outF[ROWS * (K + 1)];  // 12.9 KB staged output slab
    __shared__ float cnL[ROWS];             // ||c_row||^2
    float* ct = (float*)dotH;               // [128][33] c-slice; dead before park

    const int tid  = threadIdx.x;
    const int lane = tid & 63;
    const int w    = tid >> 6;            // wave 0..7, owns cols [w*128, +128)
    const int n    = blockIdx.x & 7;      // XCD-pinned
    const int tA   = blockIdx.x >> 3;     // rows [tA*32, +32)
    const int t0   = tA << 5;
    const int ntg0 = (n << 10) + t0;

    // --- coalesced staging ---
    const float2* zp2 = (const float2*)zp + ((size_t)n << 10);
    for (int i = tid; i < L; i += 512) {
        float2 tv = zp2[i];
        float tn = tv.x + tv.y;
        ztn[i] = tn;
        ztr[i] = rsqrtf(fmaxf(tn, EPS * EPS));
    }
    const int* nb = neg_inds + (size_t)ntg0 * K;
    for (int i = tid; i < ROWS * K; i += 512) nil[i] = nb[i];

    // --- own c-slice: 128 ch x 32 t, coalesced 32-B per thread ---
    {
        const int ch = tid >> 2;
        const int j0 = (tid & 3) * 8;
        const float* cr = c_orig + ((size_t)(n * C + ch)) * (L + 1) + t0 + 1 + j0;
#pragma unroll
        for (int jj = 0; jj < 8; jj++) ct[ch * 33 + j0 + jj] = cr[jj];
    }
    __syncthreads();

    // --- A fragments + c-norms from ct ---
    const int r16 = lane & 15;
    const int kg  = lane >> 4;
    half8 a[2][4];
#pragma unroll
    for (int at = 0; at < 2; at++)
#pragma unroll
        for (int ks = 0; ks < 4; ks++)
#pragma unroll
            for (int e = 0; e < 8; e++)
                a[at][ks][e] = (_Float16)ct[(ks * 32 + kg * 8 + e) * 33 + (at << 4) + r16];
    {
        const int row = tid >> 4, sub = tid & 15;
        float cs = 0.f;
#pragma unroll
        for (int i = 0; i < 8; i++) {
            float v = ct[(sub * 8 + i) * 33 + row];
            cs += v * v;
        }
        cs += __shfl_xor(cs, 1); cs += __shfl_xor(cs, 2);
        cs += __shfl_xor(cs, 4); cs += __shfl_xor(cs, 8);
        if (sub == 0) cnL[row] = cs;
    }
    __syncthreads();   // ct reads complete before dotH park overwrites it

    // --- GEMM: B from zf (XCD-L2-resident), fully coalesced ---
    const size_t nbase = (size_t)n << 14;
    f32x4 acc[2][8];
#pragma unroll
    for (int at = 0; at < 2; at++)
#pragma unroll
        for (int i = 0; i < 8; i++)
#pragma unroll
            for (int r = 0; r < 4; r++) acc[at][i][r] = 0.f;

#pragma unroll
    for (int ks = 0; ks < 4; ks++) {
        half8 b[8];
#pragma unroll
        for (int nt = 0; nt < 8; nt++)
            b[nt] = zf[nbase + ((size_t)(((w << 3) + nt) * 4 + ks) << 6) + lane];
#pragma unroll
        for (int nt = 0; nt < 8; nt++)
            acc[0][nt] = __builtin_amdgcn_mfma_f32_16x16x32_f16(a[0][ks], b[nt], acc[0][nt], 0, 0, 0);
#pragma unroll
        for (int nt = 0; nt < 8; nt++)
            acc[1][nt] = __builtin_amdgcn_mfma_f32_16x16x32_f16(a[1][ks], b[nt], acc[1][nt], 0, 0, 0);
    }

    // --- park dot tile (kg-swizzled cols; 2 lanes/dword: free) ---
#pragma unroll
    for (int at = 0; at < 2; at++)
#pragma unroll
        for (int nt = 0; nt < 8; nt++)
#pragma unroll
            for (int r = 0; r < 4; r++) {
                const int row = (at << 4) + (kg << 2) + r;
                const int col = (w << 7) + (nt << 4) + r16;
                dotH[row * L + (col ^ (kg << 4))] = (_Float16)acc[at][nt][r];
            }
    __syncthreads();

    // --- gather: 16 threads per c-row, 7 targets each ---
    const int row = tid >> 4;
    const int sub = tid & 15;
    const int t   = t0 + row;
    const int ksw = ((row >> 2) & 3) << 4;   // kg-swizzle for this row
    const float cn = cnL[row];
    const float rs_c = 2.0f * rsqrtf(fmaxf(cn, EPS * EPS));

#pragma unroll
    for (int j = 0; j < 7; j++) {
        const int kk = sub * 7 + j;
        if (kk <= K) {
            const int col = (kk == 0) ? t : nil[row * K + kk - 1];
            const float dot = (float)dotH[row * L + (col ^ ksw)];
            const float tn = ztn[col];
            float logit = dot * rs_c * ztr[col];
            if (kk > 0) {
                const float ds = cn - 2.f * dot + tn;   // ~0 iff c == z_col
                if (ds < 0.05f * cn) {                  // rare: exact recheck
                    bool eq = true;
                    for (int q = 0; q < C; q++) {
                        float cv = c_orig[((size_t)(n * C + q)) * (L + 1) + t + 1];
                        float zv = z_orig[((size_t)(n * C + q)) * L + col];
                        eq = eq && (cv == zv);
                    }
                    if (eq) logit = -INFINITY;
                }
            }
            outF[row * (K + 1) + kk] = logit;
        }
    }
    __syncthreads();

    // --- flat coalesced writeback of contiguous 32x101 slab ---
    float* ob = out + (size_t)ntg0 * (K + 1);
    for (int i = tid; i < ROWS * (K + 1); i += 512) ob[i] = outF[i];
}

extern "C" void kernel_launch(void* const* d_in, const int* in_sizes, int n_in,
                              void* d_out, int out_size, void* d_ws, size_t ws_size,
                              hipStream_t stream) {
    const float* z   = (const float*)d_in[0];   // (N, C, L)
    const float* c   = (const float*)d_in[1];   // (N, C, L+1)
    const int*   neg = (const int*)d_in[2];     // (N, L, K)
    float* out = (float*)d_out;                 // (N*L, K+1)

    half8* zf = (half8*)d_ws;                   // fragment-layout z, 2 MB
    float* zp = (float*)(zf + (size_t)N * 16384);  // (N*L, 2) fp32 norm partials

    transpose_z<<<dim3(256), dim3(64, 8), 0, stream>>>(z, zf, zp);
    gemm_gather<<<dim3(N * (L / ROWS)), 512, 0, stream>>>(zf, neg, zp, z, c, out);
}